// Round 12
// baseline (387.886 us; speedup 1.0000x reference)
//
#include <hip/hip_runtime.h>
#include <hip/hip_cooperative_groups.h>

namespace cg = cooperative_groups;

#define B_SZ 16384
#define D_SZ 256
#define C_SZ 2000
#define C_PAD 2048
#define MARGIN_F 1.0f
#define NBLK 1024

typedef float floatx16 __attribute__((ext_vector_type(16)));

__device__ inline void gld_lds16(const void* g, void* l) {
  __builtin_amdgcn_global_load_lds(
      (const __attribute__((address_space(1))) void*)g,
      (__attribute__((address_space(3))) void*)l, 16, 0, 0);
}

// fp8 frag-major layout for v_mfma_f32_32x32x16_fp8_fp8 (verified R11):
//   chunk(tile32, ks, lane) -> 8 fp8 bytes at base + ((tile*16 + ks)*64 + lane)*8
//   lane holds M[tile*32 + (lane&31)][ks*16 + (lane>>5)*8 + j], j=0..7

__device__ inline int2 pack8_fp8(const float* v) {
  int lo = __builtin_amdgcn_cvt_pk_fp8_f32(v[0], v[1], 0, false);
  lo = __builtin_amdgcn_cvt_pk_fp8_f32(v[2], v[3], lo, true);
  int hi = __builtin_amdgcn_cvt_pk_fp8_f32(v[4], v[5], 0, false);
  hi = __builtin_amdgcn_cvt_pk_fp8_f32(v[6], v[7], hi, true);
  return make_int2(lo, hi);
}
__device__ inline float rt_fp8(float x) {   // round-trip through fp8 e4m3
  int p = __builtin_amdgcn_cvt_pk_fp8_f32(x, x, 0, false);
  return __builtin_amdgcn_cvt_f32_fp8(p, 0);
}

// ================= fused cooperative kernel =================
// phase 1: blocks 0..511 pred->predq + gt; blocks 512..767 sig->sigq
// grid.sync()
// phase 2: all 1024 blocks: fp8 GEMM + hinge -> partial[bid]
// grid.sync()
// phase 3: block 0 reduces partials, subtracts B*MARGIN
__global__ __launch_bounds__(256, 4) void fused_all_kernel(
    const float* __restrict__ pred, const float* __restrict__ sig,
    const int* __restrict__ label, char* __restrict__ predq,
    char* __restrict__ sigq, float* __restrict__ gt,
    float* __restrict__ partial, float* __restrict__ out) {
  __shared__ float ldsP[32][260];     // 33280 B; aliased as Bs in phase 2
  __shared__ float gtS[256];
  __shared__ float red[4];
  char* Bs = (char*)&ldsP[0][0];      // 32 KB used in phase 2

  int bid = (int)blockIdx.x;
  int tid = threadIdx.x;
  int lane = tid & 63;
  int w = tid >> 6;

  // ---------------- phase 1 ----------------
  if (bid < 512) {
    // A: coalesced tile load (32 rows x 256 K fp32)
#pragma unroll
    for (int it = 0; it < 8; it++) {
      int idx = it * 1024 + tid * 4;
      int r = idx >> 8, c = idx & 255;
      *(float4*)&ldsP[r][c] = *(const float4*)(pred + (size_t)(bid * 32 + r) * D_SZ + c);
    }
    __syncthreads();
    // B: frag-major predq, 8 B/lane coalesced writes
#pragma unroll
    for (int it = 0; it < 4; it++) {
      int ch = it * 256 + tid;          // 0..1023
      int ln = ch & 63, ks = ch >> 6;   // ks 0..15
      int r = ln & 31, kb = ks * 16 + (ln >> 5) * 8;
      float v[8];
#pragma unroll
      for (int j = 0; j < 8; j++) v[j] = ldsP[r][kb + j];
      *(int2*)(predq + ((size_t)(bid * 16 + ks) * 64 + ln) * 8) = pack8_fp8(v);
    }
    // C: fp8-consistent gt; 4 waves x 8 rows
    for (int rr = 0; rr < 8; rr++) {
      int r = w * 8 + rr;
      int row = bid * 32 + r;
      int lbl = label[row];
      float s = 0.f;
#pragma unroll
      for (int i = 0; i < 4; i++)
        s += rt_fp8(ldsP[r][lane * 4 + i]) *
             rt_fp8(sig[(size_t)(lane * 4 + i) * C_SZ + lbl]);
#pragma unroll
      for (int off = 32; off > 0; off >>= 1) s += __shfl_down(s, off, 64);
      if (lane == 0) gt[row] = s;
    }
    __syncthreads();                    // ldsP reused as Bs after grid sync
  } else if (bid < 768) {
    // sigq: one 8-byte chunk per thread (65536 chunks total)
    int ch = (bid - 512) * 256 + tid;
    int ln = ch & 63, ks = (ch >> 6) & 15, ct = ch >> 10;
    int col = ct * 32 + (ln & 31);
    int kb = ks * 16 + (ln >> 5) * 8;
    float v[8];
#pragma unroll
    for (int j = 0; j < 8; j++)
      v[j] = (col < C_SZ) ? sig[(size_t)(kb + j) * C_SZ + col] : 0.f;
    *(int2*)(sigq + ((size_t)(ct * 16 + ks) * 64 + ln) * 8) = pack8_fp8(v);
  }

  cg::this_grid().sync();

  // ---------------- phase 2: GEMM + hinge ----------------
  int kh = lane >> 5, lm = lane & 31;
  int i = bid >> 3;
  int rsb = (bid & 7) * 8 + (i & 7);   // row superblock 0..63 (256 rows)
  int cg_ = i >> 3;                    // colgroup 0..15 (128 cols)

  // stage B tile (128 cols x 256 K fp8 = 32 KB), frag-major copy
#pragma unroll
  for (int s = 0; s < 8; s++) {
    int q0 = s * 256 + w * 64;         // 16 B chunk id, 0..2047
    gld_lds16(sigq + ((size_t)cg_ * 2048 + q0 + lane) * 16, (void*)(Bs + (size_t)q0 * 16));
  }
  gtS[tid] = gt[rsb * 256 + tid];      // 256 rows of gt -> LDS (saves 32 VGPR)

  // A frags: full K for 2 rowtiles (rows rsb*256 + w*64 .. +63), 64 VGPR
  long afr[2][16];
#pragma unroll
  for (int rt = 0; rt < 2; rt++)
#pragma unroll
    for (int ks = 0; ks < 16; ks++)
      afr[rt][ks] = *(const long*)(predq +
          (((size_t)(rsb * 8 + w * 2 + rt) * 16 + ks) * 64 + lane) * 8);
  __syncthreads();

  float sum = 0.f;
#pragma unroll
  for (int ct = 0; ct < 4; ct++) {
    floatx16 acc0 = {}, acc1 = {};
#pragma unroll
    for (int ks = 0; ks < 16; ks++) {
      long b = *(const long*)(Bs + (size_t)((ct * 16 + ks) * 64 + lane) * 8);
      acc0 = __builtin_amdgcn_mfma_f32_32x32x16_fp8_fp8(afr[0][ks], b, acc0, 0, 0, 0);
      acc1 = __builtin_amdgcn_mfma_f32_32x32x16_fp8_fp8(afr[1][ks], b, acc1, 0, 0, 0);
    }
    int col = cg_ * 128 + ct * 32 + lm;
    float keep = (col < C_SZ) ? 1.f : 0.f;   // padded cols: s=0 but hinge!=0
#pragma unroll
    for (int reg = 0; reg < 16; reg++) {
      int rl = (reg & 3) + 8 * (reg >> 2) + 4 * kh;
      sum += keep * fmaxf(acc0[reg] + MARGIN_F - gtS[w * 64 + rl], 0.f);
      sum += keep * fmaxf(acc1[reg] + MARGIN_F - gtS[w * 64 + 32 + rl], 0.f);
    }
  }
#pragma unroll
  for (int off = 32; off > 0; off >>= 1) sum += __shfl_down(sum, off, 64);
  if (lane == 0) red[w] = sum;
  __syncthreads();
  if (tid == 0) partial[bid] = red[0] + red[1] + red[2] + red[3];

  cg::this_grid().sync();

  // ---------------- phase 3: final reduce (block 0) ----------------
  if (bid == 0) {
    float s = 0.f;
    for (int p = tid; p < NBLK; p += 256) s += partial[p];
#pragma unroll
    for (int off = 32; off > 0; off >>= 1) s += __shfl_down(s, off, 64);
    if (lane == 0) red[w] = s;
    __syncthreads();
    if (tid == 0) out[0] = red[0] + red[1] + red[2] + red[3] - (float)B_SZ * MARGIN_F;
  }
}

// ================= fallback path (R11, proven 104 us) =================
__global__ __launch_bounds__(256) void prep_kernel(
    const float* __restrict__ pred, const float* __restrict__ sig,
    const int* __restrict__ label, char* __restrict__ predq,
    char* __restrict__ sigq, float* __restrict__ gt) {
  int bid = (int)blockIdx.x;
  int tid = threadIdx.x;
  if (bid < 512) {
    __shared__ float ldsP[32][260];
#pragma unroll
    for (int it = 0; it < 8; it++) {
      int idx = it * 1024 + tid * 4;
      int r = idx >> 8, c = idx & 255;
      *(float4*)&ldsP[r][c] = *(const float4*)(pred + (size_t)(bid * 32 + r) * D_SZ + c);
    }
    __syncthreads();
#pragma unroll
    for (int it = 0; it < 4; it++) {
      int ch = it * 256 + tid;
      int ln = ch & 63, ks = ch >> 6;
      int r = ln & 31, kb = ks * 16 + (ln >> 5) * 8;
      float v[8];
#pragma unroll
      for (int j = 0; j < 8; j++) v[j] = ldsP[r][kb + j];
      *(int2*)(predq + ((size_t)(bid * 16 + ks) * 64 + ln) * 8) = pack8_fp8(v);
    }
    int lane = tid & 63, w = tid >> 6;
    for (int rr = 0; rr < 8; rr++) {
      int r = w * 8 + rr;
      int row = bid * 32 + r;
      int lbl = label[row];
      float s = 0.f;
#pragma unroll
      for (int i = 0; i < 4; i++)
        s += rt_fp8(ldsP[r][lane * 4 + i]) *
             rt_fp8(sig[(size_t)(lane * 4 + i) * C_SZ + lbl]);
#pragma unroll
      for (int off = 32; off > 0; off >>= 1) s += __shfl_down(s, off, 64);
      if (lane == 0) gt[row] = s;
    }
  } else {
    int ct = bid - 512;
#pragma unroll
    for (int it = 0; it < 4; it++) {
      int ch = it * 256 + tid;
      int ln = ch & 63, ks = ch >> 6;
      int col = ct * 32 + (ln & 31);
      int kb = ks * 16 + (ln >> 5) * 8;
      float v[8];
#pragma unroll
      for (int j = 0; j < 8; j++)
        v[j] = (col < C_SZ) ? sig[(size_t)(kb + j) * C_SZ + col] : 0.f;
      *(int2*)(sigq + ((size_t)(ct * 16 + ks) * 64 + ln) * 8) = pack8_fp8(v);
    }
  }
}

__global__ __launch_bounds__(256) void mfma_fused_kernel(
    const char* __restrict__ predq, const char* __restrict__ sigq,
    const float* __restrict__ gt, float* __restrict__ partial) {
  __shared__ char Bs[4096 * 8];
  __shared__ float red[4];
  int tid = threadIdx.x;
  int lane = tid & 63;
  int w = tid >> 6;
  int kh = lane >> 5, lm = lane & 31;
  int bid = (int)blockIdx.x;
  int i = bid >> 3;
  int rsb = (bid & 7) * 8 + (i & 7);
  int cg_ = i >> 3;
#pragma unroll
  for (int s = 0; s < 8; s++) {
    int q0 = s * 256 + w * 64;
    gld_lds16(sigq + ((size_t)cg_ * 2048 + q0 + lane) * 16, (void*)(Bs + (size_t)q0 * 16));
  }
  long afr[2][16];
#pragma unroll
  for (int rt = 0; rt < 2; rt++)
#pragma unroll
    for (int ks = 0; ks < 16; ks++)
      afr[rt][ks] = *(const long*)(predq +
          (((size_t)(rsb * 8 + w * 2 + rt) * 16 + ks) * 64 + lane) * 8);
  float mgv[2][16];
#pragma unroll
  for (int rt = 0; rt < 2; rt++)
#pragma unroll
    for (int reg = 0; reg < 16; reg++) {
      int row = rsb * 256 + w * 64 + rt * 32 + (reg & 3) + 8 * (reg >> 2) + 4 * kh;
      mgv[rt][reg] = MARGIN_F - gt[row];
    }
  __syncthreads();
  float sum = 0.f;
#pragma unroll
  for (int ct = 0; ct < 4; ct++) {
    floatx16 acc0 = {}, acc1 = {};
#pragma unroll
    for (int ks = 0; ks < 16; ks++) {
      long b = *(const long*)(Bs + (size_t)((ct * 16 + ks) * 64 + lane) * 8);
      acc0 = __builtin_amdgcn_mfma_f32_32x32x16_fp8_fp8(afr[0][ks], b, acc0, 0, 0, 0);
      acc1 = __builtin_amdgcn_mfma_f32_32x32x16_fp8_fp8(afr[1][ks], b, acc1, 0, 0, 0);
    }
    int col = cg_ * 128 + ct * 32 + lm;
    float keep = (col < C_SZ) ? 1.f : 0.f;
#pragma unroll
    for (int reg = 0; reg < 16; reg++) {
      sum += keep * fmaxf(acc0[reg] + mgv[0][reg], 0.f);
      sum += keep * fmaxf(acc1[reg] + mgv[1][reg], 0.f);
    }
  }
#pragma unroll
  for (int off = 32; off > 0; off >>= 1) sum += __shfl_down(sum, off, 64);
  if (lane == 0) red[w] = sum;
  __syncthreads();
  if (tid == 0) partial[bid] = red[0] + red[1] + red[2] + red[3];
}

__global__ __launch_bounds__(256) void reduce_kernel(
    const float* __restrict__ partial, float* __restrict__ out) {
  int tid = threadIdx.x;
  float s = 0.f;
  for (int i = tid * 4; i < NBLK; i += 1024) {
    float4 p = *(const float4*)(partial + i);
    s += p.x + p.y + p.z + p.w;
  }
#pragma unroll
  for (int off = 32; off > 0; off >>= 1) s += __shfl_down(s, off, 64);
  __shared__ float red[4];
  if ((tid & 63) == 0) red[tid >> 6] = s;
  __syncthreads();
  if (tid == 0) out[0] = red[0] + red[1] + red[2] + red[3] - (float)B_SZ * MARGIN_F;
}

extern "C" void kernel_launch(void* const* d_in, const int* in_sizes, int n_in,
                              void* d_out, int out_size, void* d_ws, size_t ws_size,
                              hipStream_t stream) {
  const float* pred  = (const float*)d_in[0];   // (B, D) fp32
  const int*   label = (const int*)d_in[1];     // (B,)
  // d_in[2] = train_classes = arange(C), unused
  const float* sig   = (const float*)d_in[3];   // (D, C) fp32
  float* out = (float*)d_out;

  float* gt      = (float*)d_ws;                                   // 64 KB
  float* partial = (float*)((char*)d_ws + (64 << 10));             // 4 KB
  char*  predq   = (char*)d_ws + (128 << 10);                      // 4 MB
  char*  sigq    = (char*)d_ws + (128 << 10) + (4 << 20);          // 512 KB

  void* args[] = {(void*)&pred, (void*)&sig, (void*)&label, (void*)&predq,
                  (void*)&sigq, (void*)&gt, (void*)&partial, (void*)&out};
  hipError_t err = hipLaunchCooperativeKernel(
      (const void*)fused_all_kernel, dim3(NBLK), dim3(256), args, 0, stream);
  if (err != hipSuccess) {
    // fallback: proven R11 3-kernel path
    prep_kernel<<<576, 256, 0, stream>>>(pred, sig, label, predq, sigq, gt);
    mfma_fused_kernel<<<NBLK, 256, 0, stream>>>(predq, sigq, gt, partial);
    reduce_kernel<<<1, 256, 0, stream>>>(partial, out);
  }
}

// Round 14
// 97.953 us; speedup vs baseline: 3.9599x; 3.9599x over previous
//
#include <hip/hip_runtime.h>

#define B_SZ 16384
#define D_SZ 256
#define C_SZ 2000
#define C_PAD 2048
#define MARGIN_F 1.0f
#define NBLK 1024

typedef float floatx16 __attribute__((ext_vector_type(16)));

__device__ inline void gld_lds16(const void* g, void* l) {
  __builtin_amdgcn_global_load_lds(
      (const __attribute__((address_space(1))) void*)g,
      (__attribute__((address_space(3))) void*)l, 16, 0, 0);
}

// fp8 frag-major layout for v_mfma_f32_32x32x16_fp8_fp8 (verified R11):
//   chunk(tile32, ks, lane) -> 8 fp8 bytes at base + ((tile*16 + ks)*64 + lane)*8
//   lane holds M[tile*32 + (lane&31)][ks*16 + (lane>>5)*8 + j], j=0..7
// Column c of M: its 256 k-values live in 32 chunks of 8 B (2 KB of lines vs
// 16 KB gathering fp32 sig at stride 8 KB) -- used by prep's gt gather.

__device__ inline int2 pack8_fp8(const float* v) {
  int lo = __builtin_amdgcn_cvt_pk_fp8_f32(v[0], v[1], 0, false);
  lo = __builtin_amdgcn_cvt_pk_fp8_f32(v[2], v[3], lo, true);
  int hi = __builtin_amdgcn_cvt_pk_fp8_f32(v[4], v[5], 0, false);
  hi = __builtin_amdgcn_cvt_pk_fp8_f32(v[6], v[7], hi, true);
  return make_int2(lo, hi);
}
__device__ inline float rt_fp8(float x) {   // round-trip through fp8 e4m3
  int p = __builtin_amdgcn_cvt_pk_fp8_f32(x, x, 0, false);
  return __builtin_amdgcn_cvt_f32_fp8(p, 0);
}
// unpack 4 fp8 bytes of a word with literal selectors (builtin requires
// constant byte index -- R13 compile-fail lesson)
__device__ inline void unpack4_fp8(int w, float* o) {
  o[0] = __builtin_amdgcn_cvt_f32_fp8(w, 0);
  o[1] = __builtin_amdgcn_cvt_f32_fp8(w, 1);
  o[2] = __builtin_amdgcn_cvt_f32_fp8(w, 2);
  o[3] = __builtin_amdgcn_cvt_f32_fp8(w, 3);
}

// ---- kernel 1: sig (D x C) fp32 -> sigq frag-major fp8; zero out[0] ----
__global__ __launch_bounds__(256) void sigq_kernel(
    const float* __restrict__ sig, char* __restrict__ sigq,
    float* __restrict__ out) {
  int t = blockIdx.x * 256 + threadIdx.x;   // 65536 chunks of 8 B
  if (t == 0) out[0] = 0.f;
  int ln = t & 63, ks = (t >> 6) & 15, ct = t >> 10;
  int col = ct * 32 + (ln & 31);
  int kb = ks * 16 + (ln >> 5) * 8;
  float v[8];
#pragma unroll
  for (int j = 0; j < 8; j++)
    v[j] = (col < C_SZ) ? sig[(size_t)(kb + j) * C_SZ + col] : 0.f;
  *(int2*)(sigq + (size_t)t * 8) = pack8_fp8(v);
}

// ---- kernel 2: prep — pred -> LDS -> predq (frag-major fp8) + gt ----
// gt[b] = fp32 dot of fp8(pred[b]) (from LDS) and fp8 sig column label_b
// (read from sigq -> exactly the values the MFMA consumes). The GEMM runs
// unmasked; the label column's hinge == MARGIN + eps, subtracted as the
// constant B_SZ*MARGIN (algebra validated R9/R11).
__global__ __launch_bounds__(256) void prep_kernel(
    const float* __restrict__ pred, const char* __restrict__ sigq,
    const int* __restrict__ label, char* __restrict__ predq,
    float* __restrict__ gt) {
  __shared__ float ldsP[32][260];   // +4 pad, float4-aligned rows
  int bid = (int)blockIdx.x;
  int tid = threadIdx.x;
  int lane = tid & 63;
  int w = tid >> 6;
  // phase A: coalesced tile load (32 rows x 256 K fp32)
#pragma unroll
  for (int it = 0; it < 8; it++) {
    int idx = it * 1024 + tid * 4;
    int r = idx >> 8, c = idx & 255;
    *(float4*)&ldsP[r][c] = *(const float4*)(pred + (size_t)(bid * 32 + r) * D_SZ + c);
  }
  __syncthreads();
  // phase B: frag-major predq, 8 B/lane coalesced writes
#pragma unroll
  for (int it = 0; it < 4; it++) {
    int ch = it * 256 + tid;          // 0..1023
    int ln = ch & 63, ks = ch >> 6;   // ks 0..15
    int r = ln & 31, kb = ks * 16 + (ln >> 5) * 8;
    float v[8];
#pragma unroll
    for (int j = 0; j < 8; j++) v[j] = ldsP[r][kb + j];
    *(int2*)(predq + ((size_t)(bid * 16 + ks) * 64 + ln) * 8) = pack8_fp8(v);
  }
  // phase C: gt; 2 rows per wave-iteration (half-wave per row).
  // Half-lane l (0..31) owns k = l*8 .. l*8+7 == one sigq chunk (8 B).
  int l = lane & 31;
  int half = lane >> 5;
#pragma unroll
  for (int it = 0; it < 4; it++) {
    int r = w * 8 + it * 2 + half;
    int row = bid * 32 + r;
    int lbl = label[row];
    int tile = lbl >> 5, l5 = lbl & 31;
    int ks = l >> 1, kh = l & 1;
    int2 p8 = *(const int2*)(sigq +
        (((size_t)(tile * 16 + ks) * 64) + kh * 32 + l5) * 8);
    float sv[8];
    unpack4_fp8(p8.x, sv);
    unpack4_fp8(p8.y, sv + 4);
    float s = 0.f;
#pragma unroll
    for (int j = 0; j < 8; j++)
      s += rt_fp8(ldsP[r][l * 8 + j]) * sv[j];
#pragma unroll
    for (int off = 16; off > 0; off >>= 1) s += __shfl_down(s, off, 32);
    if (l == 0) gt[row] = s;
  }
}

// ---- kernel 3: GEMM + hinge (fp8), atomic tail into out ----
// block = 256 rows x 128 cols, 4 waves; wave = 64 rows (2 rowtiles) x 128.
// B-tile in LDS once (32 KB, 1 barrier); full-K A frags in regs (64 VGPR).
// One atomicAdd(out) per block (1024 spread over finish times, ~13 ns each).
__global__ __launch_bounds__(256) void mfma_fused_kernel(
    const char* __restrict__ predq, const char* __restrict__ sigq,
    const float* __restrict__ gt, float* __restrict__ out) {
  __shared__ char Bs[4096 * 8];   // 32 KB
  __shared__ float red[4];
  int tid = threadIdx.x;
  int lane = tid & 63;
  int w = tid >> 6;
  int kh = lane >> 5, lm = lane & 31;
  int bid = (int)blockIdx.x;
  int i = bid >> 3;
  int rsb = (bid & 7) * 8 + (i & 7);   // row superblock 0..63 (256 rows)
  int cg = i >> 3;                     // colgroup 0..15 (128 cols)

  // stage B tile (128 cols x 256 K fp8 = 32 KB), straight frag-major copy
#pragma unroll
  for (int s = 0; s < 8; s++) {
    int q0 = s * 256 + w * 64;         // 16 B chunk id, 0..2047
    gld_lds16(sigq + ((size_t)cg * 2048 + q0 + lane) * 16, (void*)(Bs + (size_t)q0 * 16));
  }

  // A frags: full K for 2 rowtiles (rows rsb*256 + w*64 .. +63), 64 VGPR
  long afr[2][16];
#pragma unroll
  for (int rt = 0; rt < 2; rt++)
#pragma unroll
    for (int ks = 0; ks < 16; ks++)
      afr[rt][ks] = *(const long*)(predq +
          (((size_t)(rsb * 8 + w * 2 + rt) * 16 + ks) * 64 + lane) * 8);

  // mg = margin - gt for the rows this lane owns (C/D row map, verified R3)
  float mgv[2][16];
#pragma unroll
  for (int rt = 0; rt < 2; rt++)
#pragma unroll
    for (int reg = 0; reg < 16; reg++) {
      int row = rsb * 256 + w * 64 + rt * 32 + (reg & 3) + 8 * (reg >> 2) + 4 * kh;
      mgv[rt][reg] = MARGIN_F - gt[row];
    }
  __syncthreads();

  float sum = 0.f;
#pragma unroll
  for (int ct = 0; ct < 4; ct++) {
    floatx16 acc0 = {}, acc1 = {};
#pragma unroll
    for (int ks = 0; ks < 16; ks++) {
      long b = *(const long*)(Bs + (size_t)((ct * 16 + ks) * 64 + lane) * 8);
      acc0 = __builtin_amdgcn_mfma_f32_32x32x16_fp8_fp8(afr[0][ks], b, acc0, 0, 0, 0);
      acc1 = __builtin_amdgcn_mfma_f32_32x32x16_fp8_fp8(afr[1][ks], b, acc1, 0, 0, 0);
    }
    int col = cg * 128 + ct * 32 + lm;
    float keep = (col < C_SZ) ? 1.f : 0.f;   // padded cols: s=0 but hinge!=0
#pragma unroll
    for (int reg = 0; reg < 16; reg++) {
      sum += keep * fmaxf(acc0[reg] + mgv[0][reg], 0.f);
      sum += keep * fmaxf(acc1[reg] + mgv[1][reg], 0.f);
    }
  }
#pragma unroll
  for (int off = 32; off > 0; off >>= 1) sum += __shfl_down(sum, off, 64);
  if (lane == 0) red[w] = sum;
  __syncthreads();
  // per-block share of the label-column constant: B_SZ*MARGIN / NBLK = 16
  if (tid == 0)
    atomicAdd(out, red[0] + red[1] + red[2] + red[3]
                   - (float)B_SZ * MARGIN_F / (float)NBLK);
}

extern "C" void kernel_launch(void* const* d_in, const int* in_sizes, int n_in,
                              void* d_out, int out_size, void* d_ws, size_t ws_size,
                              hipStream_t stream) {
  const float* pred  = (const float*)d_in[0];   // (B, D) fp32
  const int*   label = (const int*)d_in[1];     // (B,)
  // d_in[2] = train_classes = arange(C), unused
  const float* sig   = (const float*)d_in[3];   // (D, C) fp32
  float* out = (float*)d_out;

  float* gt    = (float*)d_ws;                                   // 64 KB
  char*  predq = (char*)d_ws + (128 << 10);                      // 4 MB
  char*  sigq  = (char*)d_ws + (128 << 10) + (4 << 20);          // 512 KB

  sigq_kernel<<<256, 256, 0, stream>>>(sig, sigq, out);
  prep_kernel<<<512, 256, 0, stream>>>(pred, sigq, label, predq, gt);
  mfma_fused_kernel<<<NBLK, 256, 0, stream>>>(predq, sigq, gt, out);
}

// Round 15
// 96.033 us; speedup vs baseline: 4.0391x; 1.0200x over previous
//
#include <hip/hip_runtime.h>

#define B_SZ 16384
#define D_SZ 256
#define C_SZ 2000
#define C_PAD 2048
#define MARGIN_F 1.0f
#define NBLK 1024

typedef float floatx16 __attribute__((ext_vector_type(16)));

__device__ inline void gld_lds16(const void* g, void* l) {
  __builtin_amdgcn_global_load_lds(
      (const __attribute__((address_space(1))) void*)g,
      (__attribute__((address_space(3))) void*)l, 16, 0, 0);
}

// fp8 frag-major layout for v_mfma_f32_32x32x16_fp8_fp8 (verified R11-R14):
//   chunk(tile32, ks, lane) -> 8 fp8 bytes at base + ((tile*16 + ks)*64 + lane)*8
//   lane holds M[tile*32 + (lane&31)][ks*16 + (lane>>5)*8 + j], j=0..7

__device__ inline int2 pack8_fp8(const float* v) {
  int lo = __builtin_amdgcn_cvt_pk_fp8_f32(v[0], v[1], 0, false);
  lo = __builtin_amdgcn_cvt_pk_fp8_f32(v[2], v[3], lo, true);
  int hi = __builtin_amdgcn_cvt_pk_fp8_f32(v[4], v[5], 0, false);
  hi = __builtin_amdgcn_cvt_pk_fp8_f32(v[6], v[7], hi, true);
  return make_int2(lo, hi);
}
__device__ inline float rt_fp8(float x) {   // round-trip through fp8 e4m3
  int p = __builtin_amdgcn_cvt_pk_fp8_f32(x, x, 0, false);
  return __builtin_amdgcn_cvt_f32_fp8(p, 0);
}
__device__ inline void unpack4_fp8(int w, float* o) {  // literal selectors only
  o[0] = __builtin_amdgcn_cvt_f32_fp8(w, 0);
  o[1] = __builtin_amdgcn_cvt_f32_fp8(w, 1);
  o[2] = __builtin_amdgcn_cvt_f32_fp8(w, 2);
  o[3] = __builtin_amdgcn_cvt_f32_fp8(w, 3);
}

// ---- kernel 1: sig (D x C) fp32 -> sigq frag-major fp8; zero out[0] ----
__global__ __launch_bounds__(256) void sigq_kernel(
    const float* __restrict__ sig, char* __restrict__ sigq,
    float* __restrict__ out) {
  int t = blockIdx.x * 256 + threadIdx.x;   // 65536 chunks of 8 B
  if (t == 0) out[0] = 0.f;
  int ln = t & 63, ks = (t >> 6) & 15, ct = t >> 10;
  int col = ct * 32 + (ln & 31);
  int kb = ks * 16 + (ln >> 5) * 8;
  float v[8];
#pragma unroll
  for (int j = 0; j < 8; j++)
    v[j] = (col < C_SZ) ? sig[(size_t)(kb + j) * C_SZ + col] : 0.f;
  *(int2*)(sigq + (size_t)t * 8) = pack8_fp8(v);
}

// ---- kernel 2: prep — 1024 blocks x 16 rows (2x the TLP of R14's 512x32)
// pred -> LDS -> predq (frag-major fp8) + gt (fp8-consistent, from sigq).
// GEMM runs unmasked; label column's hinge == MARGIN + eps, subtracted as
// the constant B_SZ*MARGIN in the GEMM tail (algebra validated R9/R11/R14).
__global__ __launch_bounds__(256) void prep_kernel(
    const float* __restrict__ pred, const char* __restrict__ sigq,
    const int* __restrict__ label, char* __restrict__ predq,
    float* __restrict__ gt) {
  __shared__ float ldsP[16][260];   // 16.6 KB -> up to 8 blocks/CU
  int bid = (int)blockIdx.x;
  int tid = threadIdx.x;
  int lane = tid & 63;
  int w = tid >> 6;
  int tile = bid >> 1;              // 32-row frag tile
  int rhi = (bid & 1) * 16;         // which half of the tile these 16 rows are
  // phase A: coalesced tile load (16 rows x 256 K fp32 = 16 KB)
#pragma unroll
  for (int it = 0; it < 4; it++) {
    int idx = it * 1024 + tid * 4;
    int r = idx >> 8, c = idx & 255;
    *(float4*)&ldsP[r][c] = *(const float4*)(pred + (size_t)(bid * 16 + r) * D_SZ + c);
  }
  __syncthreads();
  // phase B: frag-major predq; 512 chunks of 8 B (2 per thread),
  // consecutive 16 tids -> 16 consecutive lanes -> 128 B segments
#pragma unroll
  for (int it = 0; it < 2; it++) {
    int ch = it * 256 + tid;          // 0..511
    int ri = ch & 15;                 // row within our 16
    int ks = (ch >> 4) & 15;
    int kh = ch >> 8;
    int kb = ks * 16 + kh * 8;
    int ln = kh * 32 + rhi + ri;
    float v[8];
#pragma unroll
    for (int j = 0; j < 8; j++) v[j] = ldsP[ri][kb + j];
    *(int2*)(predq + ((size_t)(tile * 16 + ks) * 64 + ln) * 8) = pack8_fp8(v);
  }
  // phase C: gt; half-wave per row, lane l owns one 8-byte sigq chunk
  int l = lane & 31;
  int half = lane >> 5;
#pragma unroll
  for (int it = 0; it < 2; it++) {
    int r = w * 4 + it * 2 + half;    // 0..15
    int row = bid * 16 + r;
    int lbl = label[row];
    int ltile = lbl >> 5, l5 = lbl & 31;
    int ks = l >> 1, kh = l & 1;
    int2 p8 = *(const int2*)(sigq +
        (((size_t)(ltile * 16 + ks) * 64) + kh * 32 + l5) * 8);
    float sv[8];
    unpack4_fp8(p8.x, sv);
    unpack4_fp8(p8.y, sv + 4);
    float s = 0.f;
#pragma unroll
    for (int j = 0; j < 8; j++)
      s += rt_fp8(ldsP[r][l * 8 + j]) * sv[j];
#pragma unroll
    for (int off = 16; off > 0; off >>= 1) s += __shfl_down(s, off, 32);
    if (l == 0) gt[row] = s;
  }
}

// ---- kernel 3: GEMM + hinge (fp8), atomic tail into out ----
// block = 256 rows x 128 cols, 4 waves; wave = 64 rows (2 rowtiles) x 128.
// B-tile in LDS once (32 KB, 1 barrier); full-K A frags in regs (64 VGPR).
// One atomicAdd(out) per block (1024 spread over finish times, ~13 ns each).
__global__ __launch_bounds__(256) void mfma_fused_kernel(
    const char* __restrict__ predq, const char* __restrict__ sigq,
    const float* __restrict__ gt, float* __restrict__ out) {
  __shared__ char Bs[4096 * 8];   // 32 KB
  __shared__ float red[4];
  int tid = threadIdx.x;
  int lane = tid & 63;
  int w = tid >> 6;
  int kh = lane >> 5, lm = lane & 31;
  int bid = (int)blockIdx.x;
  int i = bid >> 3;
  int rsb = (bid & 7) * 8 + (i & 7);   // row superblock 0..63 (256 rows)
  int cg = i >> 3;                     // colgroup 0..15 (128 cols)

  // stage B tile (128 cols x 256 K fp8 = 32 KB), straight frag-major copy
#pragma unroll
  for (int s = 0; s < 8; s++) {
    int q0 = s * 256 + w * 64;         // 16 B chunk id, 0..2047
    gld_lds16(sigq + ((size_t)cg * 2048 + q0 + lane) * 16, (void*)(Bs + (size_t)q0 * 16));
  }

  // A frags: full K for 2 rowtiles (rows rsb*256 + w*64 .. +63), 64 VGPR
  long afr[2][16];
#pragma unroll
  for (int rt = 0; rt < 2; rt++)
#pragma unroll
    for (int ks = 0; ks < 16; ks++)
      afr[rt][ks] = *(const long*)(predq +
          (((size_t)(rsb * 8 + w * 2 + rt) * 16 + ks) * 64 + lane) * 8);

  // mg = margin - gt for the rows this lane owns (C/D row map, verified R3)
  float mgv[2][16];
#pragma unroll
  for (int rt = 0; rt < 2; rt++)
#pragma unroll
    for (int reg = 0; reg < 16; reg++) {
      int row = rsb * 256 + w * 64 + rt * 32 + (reg & 3) + 8 * (reg >> 2) + 4 * kh;
      mgv[rt][reg] = MARGIN_F - gt[row];
    }
  __syncthreads();

  float sum = 0.f;
#pragma unroll
  for (int ct = 0; ct < 4; ct++) {
    floatx16 acc0 = {}, acc1 = {};
#pragma unroll
    for (int ks = 0; ks < 16; ks++) {
      long b = *(const long*)(Bs + (size_t)((ct * 16 + ks) * 64 + lane) * 8);
      acc0 = __builtin_amdgcn_mfma_f32_32x32x16_fp8_fp8(afr[0][ks], b, acc0, 0, 0, 0);
      acc1 = __builtin_amdgcn_mfma_f32_32x32x16_fp8_fp8(afr[1][ks], b, acc1, 0, 0, 0);
    }
    int col = cg * 128 + ct * 32 + lm;
    float keep = (col < C_SZ) ? 1.f : 0.f;   // padded cols: s=0 but hinge!=0
#pragma unroll
    for (int reg = 0; reg < 16; reg++) {
      sum += keep * fmaxf(acc0[reg] + mgv[0][reg], 0.f);
      sum += keep * fmaxf(acc1[reg] + mgv[1][reg], 0.f);
    }
  }
#pragma unroll
  for (int off = 32; off > 0; off >>= 1) sum += __shfl_down(sum, off, 64);
  if (lane == 0) red[w] = sum;
  __syncthreads();
  // per-block share of the label-column constant: B_SZ*MARGIN / NBLK = 16
  if (tid == 0)
    atomicAdd(out, red[0] + red[1] + red[2] + red[3]
                   - (float)B_SZ * MARGIN_F / (float)NBLK);
}

extern "C" void kernel_launch(void* const* d_in, const int* in_sizes, int n_in,
                              void* d_out, int out_size, void* d_ws, size_t ws_size,
                              hipStream_t stream) {
  const float* pred  = (const float*)d_in[0];   // (B, D) fp32
  const int*   label = (const int*)d_in[1];     // (B,)
  // d_in[2] = train_classes = arange(C), unused
  const float* sig   = (const float*)d_in[3];   // (D, C) fp32
  float* out = (float*)d_out;

  float* gt    = (float*)d_ws;                                   // 64 KB
  char*  predq = (char*)d_ws + (128 << 10);                      // 4 MB
  char*  sigq  = (char*)d_ws + (128 << 10) + (4 << 20);          // 512 KB

  sigq_kernel<<<256, 256, 0, stream>>>(sig, sigq, out);
  prep_kernel<<<1024, 256, 0, stream>>>(pred, sigq, label, predq, gt);
  mfma_fused_kernel<<<NBLK, 256, 0, stream>>>(predq, sigq, gt, out);
}